// Round 6
// baseline (137.492 us; speedup 1.0000x reference)
//
#include <hip/hip_runtime.h>
#include <hip/hip_bf16.h>

#define B 4096
#define S 200
#define EMB_DIM 128
#define HIDDEN 256
#define NUM_CLASSES 20
#define VOCAB 100000
#define NSLICE 8
#define SDIM 16            // dims per slice
#define SP 224             // padded positions (ceil(200/32)*32)

typedef __attribute__((ext_vector_type(8))) unsigned short ushort8;

// RNE float -> bf16 (inputs finite)
__device__ __forceinline__ unsigned short f2bf(float f) {
    unsigned u = __float_as_uint(f);
    unsigned r = u + 0x7fffu + ((u >> 16) & 1u);
    return (unsigned short)(r >> 16);
}

// ---------------------------------------------------------------------------
// Pass 1: stream-convert the fp32 table into 8 SLICE-MAJOR bf16 arrays:
//   embh[s][v][0..16) = emb[v][16s .. 16s+16)   (each slice = 3.2 MB)
// A slice fits a single XCD's 4 MiB L2 -> pass 2 gathers L2-resident.
// 6250 blocks x 256 thr; 16 lanes/row read 512B coalesced, each lane emits
// one 16B bf16 chunk into its slice array.
// ---------------------------------------------------------------------------
__global__ __launch_bounds__(256) void convert_kernel(
    const float* __restrict__ emb,
    unsigned short* __restrict__ embh)
{
    const int t = threadIdx.x;
    const int v = blockIdx.x * 16 + (t >> 4);   // vocab row (VOCAB = 6250*16)
    const int d = t & 15;                       // 8-dim chunk 0..15
    const float4 a = *(const float4*)(emb + (long)v * EMB_DIM + d * 8);
    const float4 b = *(const float4*)(emb + (long)v * EMB_DIM + d * 8 + 4);
    ushort8 o;
    o[0] = f2bf(a.x); o[1] = f2bf(a.y); o[2] = f2bf(a.z); o[3] = f2bf(a.w);
    o[4] = f2bf(b.x); o[5] = f2bf(b.y); o[6] = f2bf(b.z); o[7] = f2bf(b.w);
    const int s = d >> 1, h = d & 1;
    *(ushort8*)(embh + (long)s * VOCAB * SDIM + (long)v * SDIM + h * 8) = o;
}

// ---------------------------------------------------------------------------
// Pass 2: sliced gather + mean-pool. Block j: slice s = j&7 (-> one slice per
// XCD under the round-robin block->XCD mapping), rows [8*(j>>3), +8).
// 4 waves x 2 rows each; lane pair (2p,2p+1) covers position p's 32B slice
// chunk (h = lane&1 -> 8 dims each). Positions >= L gather vocab row 0
// (all zeros, padding_idx=0). 5-level xor-shuffle reduce (parity-preserving),
// lanes 0/1 write the fp32 slice column of pooled.
// ---------------------------------------------------------------------------
__global__ __launch_bounds__(256) void gather_kernel(
    const int* __restrict__ x,               // [B, S]
    const int* __restrict__ lens,            // [B]
    const unsigned short* __restrict__ embh, // sliced table
    float* __restrict__ pooled)              // [B, EMB_DIM]
{
    __shared__ int sidx[8][SP];   // 7 KB
    __shared__ int sL[8];

    const int t  = threadIdx.x;
    const int s  = blockIdx.x & 7;
    const int rg = blockIdx.x >> 3;
    const unsigned short* embS = embh + (long)s * VOCAB * SDIM;

    // Stage indices for the block's 8 rows; pad with row 0 (zeros).
    {
        const int r   = t >> 5;
        const int p0  = t & 31;
        const int row = rg * 8 + r;
        const int L   = lens[row];
        if (p0 == 0) sL[r] = L;
        for (int p = p0; p < SP; p += 32)
            sidx[r][p] = (p < L) ? x[(long)row * S + p] : 0;
    }
    __syncthreads();

    const int w  = t >> 6;     // wave 0..3
    const int l  = t & 63;
    const int pl = l >> 1;     // position slot 0..31
    const int h  = l & 1;      // dim half (8 dims)

    #pragma unroll
    for (int rr = 0; rr < 2; ++rr) {
        const int r2 = 2 * w + rr;
        const int L2 = sL[r2];
        const int nR = (L2 + 31) >> 5;          // 1..7

        float acc[8];
        #pragma unroll
        for (int f = 0; f < 8; ++f) acc[f] = 0.f;

        int cur = sidx[r2][pl];
        for (int it = 0; it < nR; ++it) {
            const uint4 q = *(const uint4*)(embS + (long)cur * SDIM + h * 8);
            const int nxt = (it + 1 < nR) ? sidx[r2][pl + ((it + 1) << 5)] : 0;
            acc[0] += __uint_as_float(q.x << 16);
            acc[1] += __uint_as_float(q.x & 0xffff0000u);
            acc[2] += __uint_as_float(q.y << 16);
            acc[3] += __uint_as_float(q.y & 0xffff0000u);
            acc[4] += __uint_as_float(q.z << 16);
            acc[5] += __uint_as_float(q.z & 0xffff0000u);
            acc[6] += __uint_as_float(q.w << 16);
            acc[7] += __uint_as_float(q.w & 0xffff0000u);
            cur = nxt;
        }

        // xor strides 2..32 preserve parity bit0: reduces over the 32 lanes
        // sharing h. Every lane ends with its parity's full sum.
        #pragma unroll
        for (int st = 2; st <= 32; st <<= 1) {
            #pragma unroll
            for (int f = 0; f < 8; ++f) acc[f] += __shfl_xor(acc[f], st, 64);
        }

        if (l < 2) {   // lane 0: h=0, lane 1: h=1
            const float invL = 1.0f / (float)L2;
            float* dst = pooled + (long)(rg * 8 + r2) * EMB_DIM + s * SDIM + h * 8;
            *(float4*)dst       = make_float4(acc[0] * invL, acc[1] * invL,
                                              acc[2] * invL, acc[3] * invL);
            *(float4*)(dst + 4) = make_float4(acc[4] * invL, acc[5] * invL,
                                              acc[6] * invL, acc[7] * invL);
        }
    }
}

// ---------------------------------------------------------------------------
// Pass 3: 2-layer MLP. TB=8 rows/block -> 512 blocks. Thread t = hidden
// unit; W1 reads coalesced; pooled tile broadcast from LDS via float4.
// ---------------------------------------------------------------------------
#define TB 8
__global__ __launch_bounds__(256) void mlp_kernel(
    const float* __restrict__ pooled,
    const float* __restrict__ W1,
    const float* __restrict__ b1,
    const float* __restrict__ W2,
    const float* __restrict__ b2,
    float* __restrict__ out)
{
    __shared__ float P[TB][EMB_DIM];
    __shared__ float H[TB][HIDDEN];

    const int t = threadIdx.x;
    const int b0 = blockIdx.x * TB;

    for (int i = t; i < TB * EMB_DIM; i += 256)
        P[i >> 7][i & 127] = pooled[(long)b0 * EMB_DIM + i];
    __syncthreads();

    float acc[TB];
    #pragma unroll
    for (int r = 0; r < TB; ++r) acc[r] = 0.f;

    for (int k4 = 0; k4 < EMB_DIM; k4 += 4) {
        float4 p[TB];
        #pragma unroll
        for (int r = 0; r < TB; ++r) p[r] = *(const float4*)&P[r][k4];
        #pragma unroll
        for (int kk = 0; kk < 4; ++kk) {
            const float w = W1[(k4 + kk) * HIDDEN + t];
            #pragma unroll
            for (int r = 0; r < TB; ++r) {
                const float pv = (kk == 0) ? p[r].x : (kk == 1) ? p[r].y
                               : (kk == 2) ? p[r].z : p[r].w;
                acc[r] += pv * w;
            }
        }
    }

    const float bb = b1[t];
    #pragma unroll
    for (int r = 0; r < TB; ++r) H[r][t] = fmaxf(acc[r] + bb, 0.f);
    __syncthreads();

    if (t < TB * NUM_CLASSES) {
        const int r = t / NUM_CLASSES;
        const int c = t - r * NUM_CLASSES;
        float a0 = 0.f, a1 = 0.f;
        for (int k = 0; k < HIDDEN; k += 2) {
            a0 += H[r][k]     * W2[(k)     * NUM_CLASSES + c];
            a1 += H[r][k + 1] * W2[(k + 1) * NUM_CLASSES + c];
        }
        out[(long)(b0 + r) * NUM_CLASSES + c] = a0 + a1 + b2[c];
    }
}

extern "C" void kernel_launch(void* const* d_in, const int* in_sizes, int n_in,
                              void* d_out, int out_size, void* d_ws, size_t ws_size,
                              hipStream_t stream) {
    const int*   x    = (const int*)d_in[0];
    const int*   lens = (const int*)d_in[1];
    const float* emb  = (const float*)d_in[2];
    const float* W1   = (const float*)d_in[3];
    const float* b1   = (const float*)d_in[4];
    const float* W2   = (const float*)d_in[5];
    const float* b2   = (const float*)d_in[6];
    float*       out  = (float*)d_out;

    unsigned short* embh  = (unsigned short*)d_ws;            // 25.6 MB sliced table
    float* pooled = (float*)((char*)d_ws + (long)VOCAB * EMB_DIM * 2);  // 2 MB

    convert_kernel<<<VOCAB / 16, 256, 0, stream>>>(emb, embh);
    gather_kernel<<<(B / 8) * NSLICE, 256, 0, stream>>>(x, lens, embh, pooled);
    mlp_kernel<<<B / TB, 256, 0, stream>>>(pooled, W1, b1, W2, b2, out);
}

// Round 8
// 134.877 us; speedup vs baseline: 1.0194x; 1.0194x over previous
//
#include <hip/hip_runtime.h>
#include <hip/hip_bf16.h>

#define B 4096
#define S 200
#define EMB_DIM 128
#define HIDDEN 256
#define NUM_CLASSES 20
#define VOCAB 100000
#define NSLICE 8
#define VSLICE (VOCAB / NSLICE)   // 12500 rows = 3.2 MB bf16 -> fits one XCD L2
#define RPB 8                     // batch rows per gather block
#define LCAP 208                  // compact-list capacity (max L=199 padded to 208)

typedef __attribute__((ext_vector_type(8))) unsigned short ushort8;

// RNE float -> bf16 (inputs finite)
__device__ __forceinline__ unsigned short f2bf(float f) {
    unsigned u = __float_as_uint(f);
    unsigned r = u + 0x7fffu + ((u >> 16) & 1u);
    return (unsigned short)(r >> 16);
}

// ---------------------------------------------------------------------------
// Pass 1: stream-convert fp32 table (51.2 MB, cold each iter: the harness's
// 268 MB ws re-poison flushes L3) -> contiguous 25.6 MB bf16 table in d_ws.
// Proven structure (rounds 4/5, ~12 us).
// ---------------------------------------------------------------------------
__global__ __launch_bounds__(256) void convert_kernel(
    const float* __restrict__ emb,
    unsigned short* __restrict__ embh)
{
    const long i = ((long)blockIdx.x * 256 + threadIdx.x) * 8;
    const float4 a = *(const float4*)(emb + i);
    const float4 b = *(const float4*)(emb + i + 4);
    ushort8 o;
    o[0] = f2bf(a.x); o[1] = f2bf(a.y); o[2] = f2bf(a.z); o[3] = f2bf(a.w);
    o[4] = f2bf(b.x); o[5] = f2bf(b.y); o[6] = f2bf(b.z); o[7] = f2bf(b.w);
    *(ushort8*)(embh + i) = o;
}

// ---------------------------------------------------------------------------
// Pass 2: vocab-partitioned gather. Block j: vocab span s = j&7 (one span per
// XCD under round-robin block->XCD dispatch), batch rows [8*(j>>3), +8).
//
// Phase A (compact, barrier-bracketed, LDS-atomic): 256 threads scan the 8
//   rows' indices; in-span ones are appended to list[r] via atomicAdd on an
//   LDS counter. (Append order nondeterministic -> fp32 sum reassociation
//   only; absmax 2.4e-4 vs 9.7e-4 threshold.)
// Phase B (pad): lists padded to x16 with vocab row 0 (zeros, padding_idx=0).
// Phase C (gather): wave w gathers rows 2w,2w+1: 4 groups x 16 lanes x
//   4-deep, 256-B bf16 rows from the LOCAL 3.2 MB span (L2-resident).
//   Shuffle-reduce across groups; write partial[s][row][128] * (1/L).
// ---------------------------------------------------------------------------
__global__ __launch_bounds__(256) void gather_kernel(
    const int* __restrict__ x,               // [B, S]
    const int* __restrict__ lens,            // [B]
    const unsigned short* __restrict__ embh, // [VOCAB, EMB_DIM] bf16
    float* __restrict__ partial)             // [NSLICE, B, EMB_DIM]
{
    __shared__ int list[RPB][LCAP];   // 6.5 KB
    __shared__ int cnt[RPB];
    __shared__ int pcnt[RPB];
    __shared__ int sL[RPB];

    const int t     = threadIdx.x;
    const int slice = blockIdx.x & 7;
    const int rg    = blockIdx.x >> 3;
    const int vlo   = slice * VSLICE;

    if (t < RPB) { cnt[t] = 0; sL[t] = lens[rg * RPB + t]; }
    __syncthreads();

    // Phase A: compact. Thread t covers row r = t>>5, positions (t&31)+32j.
    {
        const int r   = t >> 5;
        const int q   = t & 31;
        const int row = rg * RPB + r;
        const int L   = sL[r];
        #pragma unroll
        for (int j = 0; j < 7; ++j) {           // 7*32 = 224 >= S
            const int p = q + 32 * j;
            if (p < L) {
                const int v = x[(long)row * S + p];
                if ((unsigned)(v - vlo) < (unsigned)VSLICE) {
                    const int pos = atomicAdd(&cnt[r], 1);
                    if (pos < LCAP) list[r][pos] = v;
                }
            }
        }
    }
    __syncthreads();

    // Phase B: pad to multiple of 16 with vocab row 0 (all zeros).
    if (t < RPB) {
        const int c  = cnt[t];
        const int cp = (c + 15) & ~15;          // <= 208 = LCAP
        for (int i = c; i < cp; ++i) list[t][i] = 0;
        pcnt[t] = cp;
    }
    __syncthreads();

    // Phase C: gather. Wave w -> rows 2w, 2w+1.
    const int w = t >> 6;
    const int l = t & 63;
    const int g = l >> 4;    // group 0..3
    const int d = l & 15;    // 16-B slot within the 256-B bf16 row

    #pragma unroll
    for (int rr = 0; rr < 2; ++rr) {
        const int r2 = 2 * w + rr;
        const int n  = pcnt[r2];

        float acc[8];
        #pragma unroll
        for (int f = 0; f < 8; ++f) acc[f] = 0.f;

        for (int base = 0; base < n; base += 16) {
            const int i0 = list[r2][base + g];
            const int i1 = list[r2][base + 4 + g];
            const int i2 = list[r2][base + 8 + g];
            const int i3 = list[r2][base + 12 + g];
            const uint4 q0 = *(const uint4*)(embh + (long)i0 * EMB_DIM + d * 8);
            const uint4 q1 = *(const uint4*)(embh + (long)i1 * EMB_DIM + d * 8);
            const uint4 q2 = *(const uint4*)(embh + (long)i2 * EMB_DIM + d * 8);
            const uint4 q3 = *(const uint4*)(embh + (long)i3 * EMB_DIM + d * 8);
            #pragma unroll
            for (int k = 0; k < 4; ++k) {
                const uint4 q = (k == 0) ? q0 : (k == 1) ? q1 : (k == 2) ? q2 : q3;
                acc[0] += __uint_as_float(q.x << 16);
                acc[1] += __uint_as_float(q.x & 0xffff0000u);
                acc[2] += __uint_as_float(q.y << 16);
                acc[3] += __uint_as_float(q.y & 0xffff0000u);
                acc[4] += __uint_as_float(q.z << 16);
                acc[5] += __uint_as_float(q.z & 0xffff0000u);
                acc[6] += __uint_as_float(q.w << 16);
                acc[7] += __uint_as_float(q.w & 0xffff0000u);
            }
        }

        // Reduce across the 4 groups (lanes sharing slot d).
        #pragma unroll
        for (int f = 0; f < 8; ++f) {
            acc[f] += __shfl_xor(acc[f], 16, 64);
            acc[f] += __shfl_xor(acc[f], 32, 64);
        }

        if (l < 16) {   // lane l holds slot l's 8 dims
            const float invL = 1.0f / (float)sL[r2];
            float* dst = partial + ((long)slice * B + (rg * RPB + r2)) * EMB_DIM + l * 8;
            *(float4*)dst       = make_float4(acc[0] * invL, acc[1] * invL,
                                              acc[2] * invL, acc[3] * invL);
            *(float4*)(dst + 4) = make_float4(acc[4] * invL, acc[5] * invL,
                                              acc[6] * invL, acc[7] * invL);
        }
    }
}

// ---------------------------------------------------------------------------
// Pass 3: sum the 8 slice partials -> pooled, then the 2-layer MLP
// (round-4 proven structure). TB=8 rows/block -> 512 blocks.
// ---------------------------------------------------------------------------
#define TB 8
__global__ __launch_bounds__(256) void mlp_kernel(
    const float* __restrict__ partial,  // [NSLICE, B, EMB_DIM]
    const float* __restrict__ W1,
    const float* __restrict__ b1,
    const float* __restrict__ W2,
    const float* __restrict__ b2,
    float* __restrict__ out)
{
    __shared__ float P[TB][EMB_DIM];
    __shared__ float H[TB][HIDDEN];

    const int t = threadIdx.x;
    const int b0 = blockIdx.x * TB;

    for (int i = t; i < TB * EMB_DIM; i += 256) {
        float s = 0.f;
        #pragma unroll
        for (int k = 0; k < NSLICE; ++k)
            s += partial[(long)k * B * EMB_DIM + (long)b0 * EMB_DIM + i];
        P[i >> 7][i & 127] = s;
    }
    __syncthreads();

    float acc[TB];
    #pragma unroll
    for (int r = 0; r < TB; ++r) acc[r] = 0.f;

    for (int k4 = 0; k4 < EMB_DIM; k4 += 4) {
        float4 p[TB];
        #pragma unroll
        for (int r = 0; r < TB; ++r) p[r] = *(const float4*)&P[r][k4];
        #pragma unroll
        for (int kk = 0; kk < 4; ++kk) {
            const float wv = W1[(k4 + kk) * HIDDEN + t];
            #pragma unroll
            for (int r = 0; r < TB; ++r) {
                const float pv = (kk == 0) ? p[r].x : (kk == 1) ? p[r].y
                               : (kk == 2) ? p[r].z : p[r].w;
                acc[r] += pv * wv;
            }
        }
    }

    const float bb = b1[t];
    #pragma unroll
    for (int r = 0; r < TB; ++r) H[r][t] = fmaxf(acc[r] + bb, 0.f);
    __syncthreads();

    if (t < TB * NUM_CLASSES) {
        const int r = t / NUM_CLASSES;
        const int c = t - r * NUM_CLASSES;
        float a0 = 0.f, a1 = 0.f;
        for (int k = 0; k < HIDDEN; k += 2) {
            a0 += H[r][k]     * W2[(k)     * NUM_CLASSES + c];
            a1 += H[r][k + 1] * W2[(k + 1) * NUM_CLASSES + c];
        }
        out[(long)(b0 + r) * NUM_CLASSES + c] = a0 + a1 + b2[c];
    }
}

extern "C" void kernel_launch(void* const* d_in, const int* in_sizes, int n_in,
                              void* d_out, int out_size, void* d_ws, size_t ws_size,
                              hipStream_t stream) {
    const int*   x    = (const int*)d_in[0];
    const int*   lens = (const int*)d_in[1];
    const float* emb  = (const float*)d_in[2];
    const float* W1   = (const float*)d_in[3];
    const float* b1   = (const float*)d_in[4];
    const float* W2   = (const float*)d_in[5];
    const float* b2   = (const float*)d_in[6];
    float*       out  = (float*)d_out;

    unsigned short* embh = (unsigned short*)d_ws;                        // 25.6 MB
    float* partial = (float*)((char*)d_ws + (long)VOCAB * EMB_DIM * 2);  // 16.8 MB

    convert_kernel<<<(VOCAB * EMB_DIM) / (8 * 256), 256, 0, stream>>>(emb, embh);
    gather_kernel<<<(B / RPB) * NSLICE, 256, 0, stream>>>(x, lens, embh, partial);
    mlp_kernel<<<B / TB, 256, 0, stream>>>(partial, W1, b1, W2, b2, out);
}

// Round 9
// 125.559 us; speedup vs baseline: 1.0950x; 1.0742x over previous
//
#include <hip/hip_runtime.h>
#include <hip/hip_bf16.h>

#define B 4096
#define S 200
#define EMB_DIM 128
#define HIDDEN 256
#define NUM_CLASSES 20
#define VOCAB 100000
#define RB 2               // batch rows per block

typedef __attribute__((ext_vector_type(8))) unsigned short ushort8;

// RNE float -> bf16 (inputs are finite)
__device__ __forceinline__ unsigned short f2bf(float f) {
    unsigned u = __float_as_uint(f);
    unsigned r = u + 0x7fffu + ((u >> 16) & 1u);
    return (unsigned short)(r >> 16);
}

// ---------------------------------------------------------------------------
// Pass 1: stream-convert the fp32 table (51.2 MB, cold every iter: the
// harness's 268 MB ws re-poison flushes L3) into a 25.6 MB bf16 table in
// d_ws. Sequential HBM at ~6 TB/s (~12 us); halves the gathered bytes and
// leaves the table L3-resident for pass 2. [proven r4, best total 125.0]
// ---------------------------------------------------------------------------
__global__ __launch_bounds__(256) void convert_kernel(
    const float* __restrict__ emb,
    unsigned short* __restrict__ embh)
{
    const long i = ((long)blockIdx.x * 256 + threadIdx.x) * 8;
    const float4 a = *(const float4*)(emb + i);
    const float4 b = *(const float4*)(emb + i + 4);
    ushort8 o;
    o[0] = f2bf(a.x); o[1] = f2bf(a.y); o[2] = f2bf(a.z); o[3] = f2bf(a.w);
    o[4] = f2bf(b.x); o[5] = f2bf(b.y); o[6] = f2bf(b.z); o[7] = f2bf(b.w);
    *(ushort8*)(embh + i) = o;
}

// ---------------------------------------------------------------------------
// Pass 2: fused gather + mean-pool + MLP, RB=2 rows per block (2048 blocks,
// 256 threads -> 8 blocks/CU, exactly one co-residency generation).
// [r4 structure — best measured across r3..r8 variants]
//
// Gather: 16 position-groups (g = t>>4) x 16 lanes (d = t&15); lane d loads
// 16 B of the 256-B bf16 row. Full rounds are 64 positions (4-deep,
// next-round indices prefetched from LDS before the vmcnt wait). NEW vs r4:
// the last partial round runs at 16-position granularity (uniform predicated
// depth 1..4) instead of padding to 64 -> ~15% fewer gather requests.
// Positions >= L use vocab row 0 (all zeros, padding_idx=0).
// ---------------------------------------------------------------------------
__global__ __launch_bounds__(256) void fused_kernel(
    const int* __restrict__ x,              // [B, S]
    const int* __restrict__ lens,           // [B]
    const unsigned short* __restrict__ embh,// [VOCAB, EMB_DIM] bf16
    const float* __restrict__ W1,           // [EMB_DIM, HIDDEN]
    const float* __restrict__ b1,           // [HIDDEN]
    const float* __restrict__ W2,           // [HIDDEN, NUM_CLASSES]
    const float* __restrict__ b2,           // [NUM_CLASSES]
    float* __restrict__ out)                // [B, NUM_CLASSES]
{
    __shared__ int   sidx[RB][256];              // 2 KB
    __shared__ float tmp[16][16][8];             // 8 KB (group, slot, dim)
    __shared__ float P[RB][EMB_DIM];             // 1 KB
    __shared__ float H[RB][HIDDEN];              // 2 KB
    __shared__ float part[RB][4][NUM_CLASSES];   // 640 B

    const int t  = threadIdx.x;
    const int b0 = blockIdx.x * RB;

    int Ls[RB];
    #pragma unroll
    for (int r = 0; r < RB; ++r) {
        Ls[r] = lens[b0 + r];
        int v = 0;
        if (t < Ls[r]) v = x[(long)(b0 + r) * S + t];   // L <= S = 200 < 256
        sidx[r][t] = v;
    }
    __syncthreads();

    const int g = t >> 4;   // position group 0..15
    const int d = t & 15;   // 16B slot within the 256B bf16 row

    for (int r = 0; r < RB; ++r) {
        const int L     = Ls[r];
        const int nFull = L >> 6;                        // full 64-rounds
        const int nT    = ((L & 63) + 15) >> 4;          // tail depth 0..4
        const int tb    = nFull << 6;                    // tail base

        float acc[4][8];
        #pragma unroll
        for (int j = 0; j < 4; ++j)
            #pragma unroll
            for (int f = 0; f < 8; ++f) acc[j][f] = 0.f;

        // ---- full 64-position rounds (4-deep, prefetched indices) ----
        int cur[4], nxt[4];
        #pragma unroll
        for (int j = 0; j < 4; ++j) cur[j] = sidx[r][g + 16 * j];

        for (int it = 0; it < nFull; ++it) {
            uint4 v[4];
            #pragma unroll
            for (int j = 0; j < 4; ++j)
                v[j] = *(const uint4*)(embh + (long)cur[j] * EMB_DIM + d * 8);

            if (it + 1 < nFull) {
                const int nb = (it + 1) << 6;
                #pragma unroll
                for (int j = 0; j < 4; ++j) nxt[j] = sidx[r][nb + g + 16 * j];
            } else {
                #pragma unroll
                for (int j = 0; j < 4; ++j) nxt[j] = 0;
            }

            #pragma unroll
            for (int j = 0; j < 4; ++j) {
                const unsigned c0 = v[j].x, c1 = v[j].y, c2 = v[j].z, c3 = v[j].w;
                acc[j][0] += __uint_as_float(c0 << 16);
                acc[j][1] += __uint_as_float(c0 & 0xffff0000u);
                acc[j][2] += __uint_as_float(c1 << 16);
                acc[j][3] += __uint_as_float(c1 & 0xffff0000u);
                acc[j][4] += __uint_as_float(c2 << 16);
                acc[j][5] += __uint_as_float(c2 & 0xffff0000u);
                acc[j][6] += __uint_as_float(c3 << 16);
                acc[j][7] += __uint_as_float(c3 & 0xffff0000u);
            }
            #pragma unroll
            for (int j = 0; j < 4; ++j) cur[j] = nxt[j];
        }

        // ---- tail round: 16-granular, uniform predication (nT 0..4) ----
        if (nT > 0) {
            int ti[4];
            #pragma unroll
            for (int j = 0; j < 4; ++j) {
                const int p = tb + g + 16 * j;           // <= 192+15+48 = 255
                ti[j] = sidx[r][p];                      // zeros beyond L
            }
            #pragma unroll
            for (int j = 0; j < 4; ++j) {
                if (j < nT) {                            // block-uniform branch
                    const uint4 q = *(const uint4*)(embh + (long)ti[j] * EMB_DIM + d * 8);
                    acc[j][0] += __uint_as_float(q.x << 16);
                    acc[j][1] += __uint_as_float(q.x & 0xffff0000u);
                    acc[j][2] += __uint_as_float(q.y << 16);
                    acc[j][3] += __uint_as_float(q.y & 0xffff0000u);
                    acc[j][4] += __uint_as_float(q.z << 16);
                    acc[j][5] += __uint_as_float(q.z & 0xffff0000u);
                    acc[j][6] += __uint_as_float(q.w << 16);
                    acc[j][7] += __uint_as_float(q.w & 0xffff0000u);
                }
            }
        }

        #pragma unroll
        for (int f = 0; f < 8; ++f)
            tmp[g][d][f] = acc[0][f] + acc[1][f] + acc[2][f] + acc[3][f];
        __syncthreads();

        if (t < EMB_DIM) {   // dim t = slot(t>>3)*8 + (t&7)
            float s = 0.f;
            #pragma unroll
            for (int gg = 0; gg < 16; ++gg) s += tmp[gg][t >> 3][t & 7];
            P[r][t] = s / (float)L;
        }
        __syncthreads();     // tmp reused by next row
    }

    // Layer 1: hidden unit t for both rows; W1 element read once per block.
    {
        float h0a = 0.f, h0b = 0.f, h1a = 0.f, h1b = 0.f;
        for (int k = 0; k < EMB_DIM; k += 2) {
            const float wa = W1[(k)     * HIDDEN + t];
            const float wb = W1[(k + 1) * HIDDEN + t];
            h0a += P[0][k] * wa;  h0b += P[0][k + 1] * wb;
            h1a += P[1][k] * wa;  h1b += P[1][k + 1] * wb;
        }
        const float bb = b1[t];
        H[0][t] = fmaxf(h0a + h0b + bb, 0.f);
        H[1][t] = fmaxf(h1a + h1b + bb, 0.f);
    }
    __syncthreads();

    // Layer 2: RB * 4 k-segments * 20 classes = 160 threads, 64-FMA chains.
    if (t < RB * 4 * NUM_CLASSES) {
        const int r  = t / (4 * NUM_CLASSES);
        const int u  = t - r * 4 * NUM_CLASSES;
        const int j  = u / NUM_CLASSES;
        const int c  = u - j * NUM_CLASSES;
        const int k0 = j * 64;
        float a = 0.f;
        for (int k = k0; k < k0 + 64; ++k)
            a += H[r][k] * W2[k * NUM_CLASSES + c];
        part[r][j][c] = a;
    }
    __syncthreads();

    if (t < RB * NUM_CLASSES) {
        const int r = t / NUM_CLASSES;
        const int c = t - r * NUM_CLASSES;
        const float a = b2[c] + part[r][0][c] + part[r][1][c]
                              + part[r][2][c] + part[r][3][c];
        out[(long)(b0 + r) * NUM_CLASSES + c] = a;
    }
}

extern "C" void kernel_launch(void* const* d_in, const int* in_sizes, int n_in,
                              void* d_out, int out_size, void* d_ws, size_t ws_size,
                              hipStream_t stream) {
    const int*   x    = (const int*)d_in[0];
    const int*   lens = (const int*)d_in[1];
    const float* emb  = (const float*)d_in[2];
    const float* W1   = (const float*)d_in[3];
    const float* b1   = (const float*)d_in[4];
    const float* W2   = (const float*)d_in[5];
    const float* b2   = (const float*)d_in[6];
    float*       out  = (float*)d_out;

    unsigned short* embh = (unsigned short*)d_ws;   // 25.6 MB bf16 table

    convert_kernel<<<(VOCAB * EMB_DIM) / (8 * 256), 256, 0, stream>>>(emb, embh);
    fused_kernel<<<B / RB, 256, 0, stream>>>(x, lens, embh, W1, b1, W2, b2, out);
}